// Round 6
// baseline (275.431 us; speedup 1.0000x reference)
//
#include <hip/hip_runtime.h>
#include <string.h>

#define ALPHA 0.2f
// B=128, L=512, FIN=FOUT=128. Global I/O fp32; internal GEMMs bf16 MFMA.

typedef short short8 __attribute__((ext_vector_type(8)));
typedef float floatx4 __attribute__((ext_vector_type(4)));
typedef int intx4 __attribute__((ext_vector_type(4)));
typedef unsigned short ushort4v __attribute__((ext_vector_type(4)));

__device__ inline unsigned short f2bf(float f) {
    unsigned int v; __builtin_memcpy(&v, &f, 4);
    v = v + 0x7FFFu + ((v >> 16) & 1u);   // RNE
    return (unsigned short)(v >> 16);
}

// ---------------------------------------------------------------------------
// Kernel 0: adjacency mask -> bf16 multiplier (1.0 / 0.0). 512 KB.
// ---------------------------------------------------------------------------
__global__ __launch_bounds__(256) void mask_kernel(const int* __restrict__ adj,
                                                   unsigned short* __restrict__ mbf)
{
    int idx = blockIdx.x * 256 + threadIdx.x;      // grid 1024 -> 262144
    mbf[idx] = adj[idx] ? (unsigned short)0x3F80 : (unsigned short)0;
}

// ---------------------------------------------------------------------------
// Kernel 1: Wh^T = (h @ W)^T via swapped MFMA operands; emits ei/ej from fp32 acc.
// grid 512 x 256 threads.
// ---------------------------------------------------------------------------
__global__ __launch_bounds__(256) void wh_kernel(const float* __restrict__ h,
                                                 const float* __restrict__ W,
                                                 const float* __restrict__ a,
                                                 unsigned short* __restrict__ wht,
                                                 float* __restrict__ ei,
                                                 float* __restrict__ ej)
{
    __shared__ __align__(16) unsigned short h_s[128][136];  // [j_local][f] bf16
    __shared__ __align__(16) unsigned short w_s[128][136];  // [o][f] bf16
    __shared__ float a_s[256];
    const int tid  = threadIdx.x;
    const int lane = tid & 63;
    const int wv   = tid >> 6;
    const int quad = lane >> 4;
    const int l16  = lane & 15;
    const int r0   = blockIdx.x * 128;
    const int b    = r0 >> 9;
    const int jb   = r0 & 511;

    const float* hbase = h + (size_t)r0 * 128;
    for (int it = 0; it < 16; ++it) {
        int idx4 = it * 256 + tid;
        floatx4 v = *(const floatx4*)(hbase + idx4 * 4);
        int row = idx4 >> 5;
        int col = (idx4 & 31) * 4;
        ushort4v u;
        for (int e = 0; e < 4; ++e) u[e] = f2bf(v[e]);
        *(ushort4v*)&h_s[row][col] = u;
    }
    for (int it = 0; it < 64; ++it) {
        int idx = it * 256 + tid;
        w_s[idx & 127][idx >> 7] = f2bf(W[idx]);
    }
    a_s[tid] = a[tid];
    __syncthreads();

    floatx4 acc[8][2];
    for (int mo = 0; mo < 8; ++mo)
        for (int n = 0; n < 2; ++n) acc[mo][n] = (floatx4)0.f;

    for (int kk = 0; kk < 4; ++kk) {
        short8 bfr[2];
        for (int n = 0; n < 2; ++n)
            bfr[n] = *(const short8*)&h_s[wv * 32 + n * 16 + l16][kk * 32 + quad * 8];
        for (int mo = 0; mo < 8; ++mo) {
            short8 afr = *(const short8*)&w_s[mo * 16 + l16][kk * 32 + quad * 8];
            acc[mo][0] = __builtin_amdgcn_mfma_f32_16x16x32_bf16(afr, bfr[0], acc[mo][0], 0, 0, 0);
            acc[mo][1] = __builtin_amdgcn_mfma_f32_16x16x32_bf16(afr, bfr[1], acc[mo][1], 0, 0, 0);
        }
    }

    for (int n = 0; n < 2; ++n) {
        float si = 0.f, sj = 0.f;
        for (int mo = 0; mo < 8; ++mo)
            for (int r = 0; r < 4; ++r) {
                int o = mo * 16 + quad * 4 + r;
                float v = acc[mo][n][r];
                si += v * a_s[o];
                sj += v * a_s[128 + o];
            }
        si += __shfl_xor(si, 16); si += __shfl_xor(si, 32);
        sj += __shfl_xor(sj, 16); sj += __shfl_xor(sj, 32);
        if (quad == 0) {
            int j = jb + wv * 32 + n * 16 + l16;
            ei[b * 512 + j] = si;
            ej[b * 512 + j] = sj;
        }
    }

    for (int mo = 0; mo < 8; ++mo)
        for (int n = 0; n < 2; ++n)
            for (int r = 0; r < 4; ++r) {
                int o = mo * 16 + quad * 4 + r;
                int j = jb + wv * 32 + n * 16 + l16;
                wht[(size_t)b * 65536 + o * 512 + j] = f2bf(acc[mo][n][r]);
            }
}

// ---------------------------------------------------------------------------
// Kernel 2: scores -> softmax -> att @ Wh -> elu.
// 16-row i-tiles: grid 4096 x 256. Each wave owns 4 rows, ALL loads batched
// up front for max memory-level parallelism. LDS ~16.9 KB.
// ---------------------------------------------------------------------------
__global__ __launch_bounds__(256) void attn_kernel(const unsigned short* __restrict__ wht,
                                                   const float* __restrict__ ei,
                                                   const float* __restrict__ ej,
                                                   const float* __restrict__ bias,
                                                   const unsigned short* __restrict__ mbf,
                                                   float* __restrict__ out)
{
    __shared__ __align__(16) unsigned short p_s[16][520];    // unnormalized probs
    __shared__ float ei_s[16];
    __shared__ float s_row[16];

    const int tid  = threadIdx.x;
    const int lane = tid & 63;
    const int wv   = tid >> 6;
    const int quad = lane >> 4;
    const int l16  = lane & 15;
    const int b    = blockIdx.x >> 5;
    const int i0   = (blockIdx.x & 31) * 16;

    // ---- Issue ALL phase-A loads up front (16 waves x 20 loads in flight) ----
    const float* bp = bias + ((size_t)(b * 512 + i0 + wv * 4)) * 512;
    const unsigned short* mp = mbf + (i0 + wv * 4) * 512;
    floatx4 b0[4], b1[4];
    ushort4v m0[4], m1[4];
#pragma unroll
    for (int r = 0; r < 4; ++r) {
        b0[r] = *(const floatx4*)(bp + r * 512 + lane * 4);
        b1[r] = *(const floatx4*)(bp + r * 512 + 256 + lane * 4);
        m0[r] = *(const ushort4v*)(mp + r * 512 + lane * 4);
        m1[r] = *(const ushort4v*)(mp + r * 512 + 256 + lane * 4);
    }
    const floatx4 ejv0 = *(const floatx4*)(ej + b * 512 + lane * 4);
    const floatx4 ejv1 = *(const floatx4*)(ej + b * 512 + 256 + lane * 4);
    if (tid < 16) ei_s[tid] = ei[b * 512 + i0 + tid];

    // ---- Issue phase-B wht prefetch (depth 4) — latency hides under phase A ----
    const unsigned short* wb0 = wht + (size_t)b * 65536 + (wv * 32 + l16) * 512 + quad * 8;
    const unsigned short* wb1 = wb0 + 16 * 512;
    short8 pb0[4], pb1[4];
#pragma unroll
    for (int s = 0; s < 4; ++s) {
        pb0[s] = *(const short8*)(wb0 + s * 32);
        pb1[s] = *(const short8*)(wb1 + s * 32);
    }
    __syncthreads();   // ei_s visibility

    // ---- Phase A compute: 4 rows from registers ----
    float rsum[4];
#pragma unroll
    for (int r = 0; r < 4; ++r) {
        const int il = wv * 4 + r;
        const float eiv = ei_s[il];
        float p[8];
#pragma unroll
        for (int e = 0; e < 4; ++e) {
            float x = eiv + ejv0[e];
            x = fmaxf(x, ALPHA * x);
            x += b0[r][e];
            float mlt; { unsigned int mv = ((unsigned int)m0[r][e]) << 16; __builtin_memcpy(&mlt, &mv, 4); }
            p[e] = __expf(x) * mlt;
        }
#pragma unroll
        for (int e = 0; e < 4; ++e) {
            float x = eiv + ejv1[e];
            x = fmaxf(x, ALPHA * x);
            x += b1[r][e];
            float mlt; { unsigned int mv = ((unsigned int)m1[r][e]) << 16; __builtin_memcpy(&mlt, &mv, 4); }
            p[4 + e] = __expf(x) * mlt;
        }
        float sm = 0.f;
#pragma unroll
        for (int e = 0; e < 8; ++e) sm += p[e];
        rsum[r] = sm;
        ushort4v pk0, pk1;
        for (int e = 0; e < 4; ++e) pk0[e] = f2bf(p[e]);
        for (int e = 0; e < 4; ++e) pk1[e] = f2bf(p[4 + e]);
        *(ushort4v*)&p_s[il][lane * 4]       = pk0;
        *(ushort4v*)&p_s[il][256 + lane * 4] = pk1;
    }
#pragma unroll
    for (int r = 0; r < 4; ++r)
        for (int off = 32; off; off >>= 1)
            rsum[r] += __shfl_xor(rsum[r], off);
    if (lane == 0)
#pragma unroll
        for (int r = 0; r < 4; ++r) s_row[wv * 4 + r] = rsum[r];
    __syncthreads();

    // ---- Phase B: C[16x128] = P[16x512] @ Wh[512x128], rolling depth-4 prefetch ----
    floatx4 acc0 = (floatx4)0.f, acc1 = (floatx4)0.f;
#pragma unroll
    for (int k16 = 0; k16 < 16; ++k16) {
        // read current fragments FIRST, then reuse the slot for step k16+4
        short8 cur0 = pb0[k16 & 3];
        short8 cur1 = pb1[k16 & 3];
        if (k16 < 12) {
            pb0[k16 & 3] = *(const short8*)(wb0 + (k16 + 4) * 32);
            pb1[k16 & 3] = *(const short8*)(wb1 + (k16 + 4) * 32);
        }
        short8 af = *(const short8*)&p_s[l16][k16 * 32 + quad * 8];
        acc0 = __builtin_amdgcn_mfma_f32_16x16x32_bf16(af, cur0, acc0, 0, 0, 0);
        acc1 = __builtin_amdgcn_mfma_f32_16x16x32_bf16(af, cur1, acc1, 0, 0, 0);
    }

    // ---- Epilogue: normalize, elu, fp32 store ----
#pragma unroll
    for (int r = 0; r < 4; ++r) {
        int il = quad * 4 + r;
        float inv = 1.f / s_row[il];
        float v0 = acc0[r] * inv;
        float v1 = acc1[r] * inv;
        v0 = v0 > 0.f ? v0 : (__expf(v0) - 1.f);
        v1 = v1 > 0.f ? v1 : (__expf(v1) - 1.f);
        size_t base = ((size_t)(b * 512 + i0 + il)) * 128;
        out[base + wv * 32 + l16]      = v0;
        out[base + wv * 32 + 16 + l16] = v1;
    }
}

// ---------------------------------------------------------------------------
extern "C" void kernel_launch(void* const* d_in, const int* in_sizes, int n_in,
                              void* d_out, int out_size, void* d_ws, size_t ws_size,
                              hipStream_t stream)
{
    const float* h    = (const float*)d_in[0];
    const float* W    = (const float*)d_in[1];
    const float* a    = (const float*)d_in[2];
    const float* bias = (const float*)d_in[3];
    const int*   adj  = (const int*)d_in[4];
    float*       out  = (float*)d_out;

    unsigned short* wht = (unsigned short*)d_ws;                    // 16.78 MB
    float* ei = (float*)((char*)d_ws + 16777216);                   // 256 KB
    float* ej = ei + 65536;                                         // 256 KB
    unsigned short* mbf = (unsigned short*)(ej + 65536);            // 512 KB

    hipLaunchKernelGGL(mask_kernel, dim3(1024), dim3(256), 0, stream, adj, mbf);
    hipLaunchKernelGGL(wh_kernel,   dim3(512),  dim3(256), 0, stream, h, W, a, wht, ei, ej);
    hipLaunchKernelGGL(attn_kernel, dim3(4096), dim3(256), 0, stream, wht, ei, ej, bias, mbf, out);
}